// Round 3
// baseline (677.397 us; speedup 1.0000x reference)
//
#include <hip/hip_runtime.h>

typedef unsigned short u16;
typedef short  bfrag  __attribute__((ext_vector_type(8), may_alias)); // 8 bf16 (MFMA A/B)
typedef unsigned long long ull_a __attribute__((may_alias));
typedef int    int_a  __attribute__((may_alias));
typedef float  f4_a   __attribute__((ext_vector_type(4), may_alias));
typedef __attribute__((ext_vector_type(4)))  float facc4;   // 16x16 C/D
typedef __attribute__((ext_vector_type(16))) float facc16;  // 32x32 C/D

#define SEQ   2048
#define NHEAD 16
#define HD    64
#define DM    1024
#define BH    64        // B*NHEAD
#define NTOK  8192      // B*SEQ

__device__ __forceinline__ u16 f2bf(float f){
  union { float f; unsigned u; } x; x.f = f;
  unsigned r = x.u + 0x7FFFu + ((x.u >> 16) & 1u);
  return (u16)(r >> 16);
}
// load 8 consecutive f32 -> bf16 MFMA half-fragment
__device__ __forceinline__ bfrag ld8f(const float* p){
  f4_a a = *(const f4_a*)p;
  f4_a b = *(const f4_a*)(p + 4);
  bfrag r;
  r[0] = (short)f2bf(a[0]); r[1] = (short)f2bf(a[1]);
  r[2] = (short)f2bf(a[2]); r[3] = (short)f2bf(a[3]);
  r[4] = (short)f2bf(b[0]); r[5] = (short)f2bf(b[1]);
  r[6] = (short)f2bf(b[2]); r[7] = (short)f2bf(b[3]);
  return r;
}
__device__ __forceinline__ unsigned long long pack4(u16 a, u16 b, u16 c, u16 d){
  return (unsigned long long)a | ((unsigned long long)b << 16)
       | ((unsigned long long)c << 32) | ((unsigned long long)d << 48);
}

// ---------------------------------------------------------------------------
// Kernel 1: per-head QKV projection (f32 in, bf16 out). One token per wave.
// A = x[h][e] (16 heads x 64), B[e][d] = w[d][e]. out = x @ w.T + bias.
// Writes q,k,v as [B,H,S,D] bf16.
__global__ __launch_bounds__(256) void k_proj(
  const float* __restrict__ vin, const float* __restrict__ kin, const float* __restrict__ qin,
  const float* __restrict__ wq, const float* __restrict__ bq,
  const float* __restrict__ wk, const float* __restrict__ bk,
  const float* __restrict__ wv, const float* __restrict__ bv,
  u16* __restrict__ qo, u16* __restrict__ ko, u16* __restrict__ vo)
{
  int tid  = threadIdx.x;
  int wid  = tid >> 6, lane = tid & 63;
  int quad = lane >> 4, col = lane & 15;
  int token = blockIdx.x * 4 + wid;
  int b = token >> 11, s = token & 2047;
  long xbase = (long)token * DM;

  bfrag aq[2], ak[2], av[2];
  #pragma unroll
  for (int ks = 0; ks < 2; ks++){
    long off = xbase + (long)col * HD + ks*32 + quad*8;   // A[m=col(head)][e chunk]
    aq[ks] = ld8f(qin + off);
    ak[ks] = ld8f(kin + off);
    av[ks] = ld8f(vin + off);
  }
  #pragma unroll
  for (int ns = 0; ns < 4; ns++){
    facc4 accq = {0.f,0.f,0.f,0.f}, acck = {0.f,0.f,0.f,0.f}, accv = {0.f,0.f,0.f,0.f};
    #pragma unroll
    for (int ks = 0; ks < 2; ks++){
      long woff = (long)(ns*16 + col) * HD + ks*32 + quad*8;  // B[n=d][e chunk] = w[d][e]
      accq = __builtin_amdgcn_mfma_f32_16x16x32_bf16(aq[ks], ld8f(wq + woff), accq, 0,0,0);
      acck = __builtin_amdgcn_mfma_f32_16x16x32_bf16(ak[ks], ld8f(wk + woff), acck, 0,0,0);
      accv = __builtin_amdgcn_mfma_f32_16x16x32_bf16(av[ks], ld8f(wv + woff), accv, 0,0,0);
    }
    int d = ns*16 + col;
    float fbq = bq[d], fbk = bk[d], fbv = bv[d];
    #pragma unroll
    for (int r = 0; r < 4; r++){
      int h = quad*4 + r;                                   // C row = head
      long o = ((long)(b*NHEAD + h) * SEQ + s) * HD + d;    // [B,H,S,D]
      qo[o] = f2bf(accq[r] + fbq);
      ko[o] = f2bf(acck[r] + fbk);
      vo[o] = f2bf(accv[r] + fbv);
    }
  }
}

// ---------------------------------------------------------------------------
// Kernel 2: V transpose [BH][S][D] -> [BH][D][S] (bf16), so PV A-frags load contiguously.
__global__ __launch_bounds__(256) void k_vtrans(
  const u16* __restrict__ vin, u16* __restrict__ vt)
{
  __shared__ __align__(16) u16 T[64*66];  // [s][d], stride 66
  int tid = threadIdx.x;
  int s0  = blockIdx.x * 64;
  int bh  = blockIdx.y;
  long ibase = ((long)bh * SEQ + s0) * HD;
  #pragma unroll
  for (int i = 0; i < 2; i++){
    int j = (tid + 256*i) * 8;
    int r = j >> 6, c = j & 63;
    bfrag v8 = *(const bfrag*)(vin + ibase + (long)r*HD + c);
    union { bfrag v; int w[4]; } u; u.v = v8;
    int_a* tp = (int_a*)&T[r*66 + c];      // 4B-aligned (c multiple of 8)
    tp[0] = u.w[0]; tp[1] = u.w[1]; tp[2] = u.w[2]; tp[3] = u.w[3];
  }
  __syncthreads();
  long obase = (long)bh * HD * SEQ + s0;
  #pragma unroll
  for (int it = 0; it < 16; it++){
    int d  = (it << 2) + (tid >> 6);
    int ss = tid & 63;
    vt[obase + (long)d * SEQ + ss] = T[ss*66 + d];   // coalesced store
  }
}

// ---------------------------------------------------------------------------
// Kernel 3: flash attention, transposed formulation with MFMA 32x32x16 (bf16 ws).
// Eᵀ = K·Qᵀ  (C col = q row -> per-lane softmax state), Oᵀ = Vᵀ·Pᵀ.
// Block: 4 waves x 32 q-rows = 128 q rows, loops 64-key tiles shared via LDS.
__global__ __launch_bounds__(256) void k_attn(
  const u16* __restrict__ qws, const u16* __restrict__ kws, const u16* __restrict__ vt,
  u16* __restrict__ aout)
{
  __shared__ __align__(16) u16 Kt[64*72];       // [key][e]
  __shared__ __align__(16) u16 Vt[64*72];       // [d][key]  (vt pre-transposed)
  __shared__ __align__(16) u16 Pt[4][32*72];    // per-wave [q][key]
  int tid = threadIdx.x;
  int wid = tid >> 6, lane = tid & 63;
  int ln = lane & 31, hh = lane >> 5;
  int bh = blockIdx.y;
  int q0 = blockIdx.x * 128 + wid * 32;
  long base = (long)bh * SEQ * HD;    // same element offset for qws/kws/vt

  bfrag qf[4];                        // B frag: Qᵀ[e][q], lane n=ln=q, k=e chunk
  #pragma unroll
  for (int ks = 0; ks < 4; ks++)
    qf[ks] = *(const bfrag*)(qws + base + (long)(q0 + ln)*HD + ks*16 + hh*8);

  facc16 OO0, OO1;
  #pragma unroll
  for (int r = 0; r < 16; r++){ OO0[r] = 0.f; OO1[r] = 0.f; }
  float m_ = -1e30f, l_ = 0.f;
  const float cs = 0.03125f * 1.4426950408889634f;  // (1/sqrt(1024)) * log2(e)

  for (int kt = 0; kt < 32; kt++){
    int k0 = kt * 64;
    __syncthreads();                      // prior tile's Vt reads done
    #pragma unroll
    for (int i = 0; i < 2; i++){
      int j = (tid + 256*i) * 8;
      int r = j >> 6, c = j & 63;
      *(bfrag*)&Kt[r*72 + c] = *(const bfrag*)(kws + base + (long)(k0 + r)*HD + c);
      *(bfrag*)&Vt[r*72 + c] = *(const bfrag*)(vt  + base + (long)r*SEQ + k0 + c);
    }
    __syncthreads();                      // staging visible

    // Eᵀ[key][q]: A = K[key][e] from LDS, B = Qᵀ from registers
    facc16 E0, E1;
    #pragma unroll
    for (int r = 0; r < 16; r++){ E0[r] = 0.f; E1[r] = 0.f; }
    #pragma unroll
    for (int ks = 0; ks < 4; ks++){
      bfrag kf0 = *(const bfrag*)&Kt[ ln      *72 + ks*16 + hh*8];
      bfrag kf1 = *(const bfrag*)&Kt[(32 + ln)*72 + ks*16 + hh*8];
      E0 = __builtin_amdgcn_mfma_f32_32x32x16_bf16(kf0, qf[ks], E0, 0,0,0);
      E1 = __builtin_amdgcn_mfma_f32_32x32x16_bf16(kf1, qf[ks], E1, 0,0,0);
    }

    // online softmax: lane owns q-row = ln; partner lane (^32) holds other 32 keys
    float tmax = E0[0];
    #pragma unroll
    for (int r = 1; r < 16; r++) tmax = fmaxf(tmax, E0[r]);
    #pragma unroll
    for (int r = 0; r < 16; r++) tmax = fmaxf(tmax, E1[r]);
    tmax = fmaxf(tmax, __shfl_xor(tmax, 32, 64));
    float Mn = fmaxf(m_, cs * tmax);
    float alpha = __builtin_amdgcn_exp2f(m_ - Mn);
    m_ = Mn;
    float rs = 0.f;
    #pragma unroll
    for (int r = 0; r < 16; r++){
      float p0 = __builtin_amdgcn_exp2f(cs*E0[r] - Mn);
      float p1 = __builtin_amdgcn_exp2f(cs*E1[r] - Mn);
      E0[r] = p0; E1[r] = p1; rs += p0 + p1;
    }
    rs += __shfl_xor(rs, 32, 64);
    l_ = l_ * alpha + rs;
    #pragma unroll
    for (int r = 0; r < 16; r++){ OO0[r] *= alpha; OO1[r] *= alpha; }

    // write Pᵀ C-layout -> Pt[q][key]; C rows (=keys) come in runs of 4 -> b64 packs
    u16* pw = &Pt[wid][ln*72];
    #pragma unroll
    for (int g = 0; g < 4; g++){
      *(ull_a*)(pw +      8*g + 4*hh) =
        pack4(f2bf(E0[4*g]), f2bf(E0[4*g+1]), f2bf(E0[4*g+2]), f2bf(E0[4*g+3]));
      *(ull_a*)(pw + 32 + 8*g + 4*hh) =
        pack4(f2bf(E1[4*g]), f2bf(E1[4*g+1]), f2bf(E1[4*g+2]), f2bf(E1[4*g+3]));
    }
    __syncthreads();   // P visible

    // Oᵀ[dv][q] += Vᵀ·Pᵀ: A = Vᵀ[dv][key] from Vt, B = Pᵀ[key][q] from Pt[q][key]
    bfrag pf[4];
    #pragma unroll
    for (int ks = 0; ks < 4; ks++)
      pf[ks] = *(const bfrag*)&Pt[wid][ln*72 + ks*16 + hh*8];
    #pragma unroll
    for (int ks = 0; ks < 4; ks++){
      bfrag vf0 = *(const bfrag*)&Vt[ ln      *72 + ks*16 + hh*8];
      bfrag vf1 = *(const bfrag*)&Vt[(32 + ln)*72 + ks*16 + hh*8];
      OO0 = __builtin_amdgcn_mfma_f32_32x32x16_bf16(vf0, pf[ks], OO0, 0,0,0);
      OO1 = __builtin_amdgcn_mfma_f32_32x32x16_bf16(vf1, pf[ks], OO1, 0,0,0);
    }
  }

  // epilogue: O[q][dv] = OOᵀ / l; store [B,S,H,D] (= (B,S,1024) h-major), bf16
  float inv = 1.0f / l_;
  int b_ = bh >> 4, h_ = bh & 15;
  long orow = ((long)(b_ * SEQ + q0 + ln) * NHEAD + h_) * HD;
  #pragma unroll
  for (int g = 0; g < 4; g++){
    *(ull_a*)(aout + orow +      8*g + 4*hh) =
      pack4(f2bf(OO0[4*g]*inv), f2bf(OO0[4*g+1]*inv), f2bf(OO0[4*g+2]*inv), f2bf(OO0[4*g+3]*inv));
    *(ull_a*)(aout + orow + 32 + 8*g + 4*hh) =
      pack4(f2bf(OO1[4*g]*inv), f2bf(OO1[4*g+1]*inv), f2bf(OO1[4*g+2]*inv), f2bf(OO1[4*g+3]*inv));
  }
}

// ---------------------------------------------------------------------------
// Kernel 4: output projection out = A @ wo.T + bo. A bf16 (ws), wo/bo/out f32.
__global__ __launch_bounds__(256) void k_oproj(
  const u16* __restrict__ ain, const float* __restrict__ wo, const float* __restrict__ bo,
  float* __restrict__ out)
{
  int tid  = threadIdx.x;
  int wid  = tid >> 6, lane = tid & 63;
  int quad = lane >> 4, col = lane & 15;
  int m0 = blockIdx.x * 64 + wid * 16;
  int n0 = blockIdx.y * 64;
  facc4 acc[4];
  #pragma unroll
  for (int ns = 0; ns < 4; ns++) acc[ns] = {0.f,0.f,0.f,0.f};
  const u16* ap = ain + (long)(m0 + col) * DM + quad*8;
  #pragma unroll 4
  for (int k0 = 0; k0 < DM; k0 += 32){
    bfrag af = *(const bfrag*)(ap + k0);
    #pragma unroll
    for (int ns = 0; ns < 4; ns++){
      bfrag bf = ld8f(wo + (long)(n0 + ns*16 + col) * DM + k0 + quad*8);
      acc[ns] = __builtin_amdgcn_mfma_f32_16x16x32_bf16(af, bf, acc[ns], 0,0,0);
    }
  }
  #pragma unroll
  for (int ns = 0; ns < 4; ns++){
    int n = n0 + ns*16 + col;
    float bias = bo[n];
    #pragma unroll
    for (int r = 0; r < 4; r++)
      out[(long)(m0 + quad*4 + r) * DM + n] = acc[ns][r] + bias;
  }
}

// ---------------------------------------------------------------------------
extern "C" void kernel_launch(void* const* d_in, const int* in_sizes, int n_in,
                              void* d_out, int out_size, void* d_ws, size_t ws_size,
                              hipStream_t stream)
{
  const float* values = (const float*)d_in[0];
  const float* keys   = (const float*)d_in[1];
  const float* query  = (const float*)d_in[2];
  const float* wq = (const float*)d_in[3];
  const float* bq = (const float*)d_in[4];
  const float* wk = (const float*)d_in[5];
  const float* bk = (const float*)d_in[6];
  const float* wv = (const float*)d_in[7];
  const float* bv = (const float*)d_in[8];
  const float* wo = (const float*)d_in[9];
  const float* bo = (const float*)d_in[10];

  const long N = 8388608;             // B*H*S*D elements
  u16* qws  = (u16*)d_ws;             // bf16 intermediates
  u16* kws  = qws  + N;
  u16* vws  = kws  + N;
  u16* vtws = vws  + N;
  u16* aws  = vws;                    // reuse vws (dead after k_vtrans): 64 MB total

  k_proj  <<<2048,          256, 0, stream>>>(values, keys, query, wq,bq, wk,bk, wv,bv,
                                              qws, kws, vws);
  k_vtrans<<<dim3(32, 64),  256, 0, stream>>>(vws, vtws);
  k_attn  <<<dim3(16, 64),  256, 0, stream>>>(qws, kws, vtws, aws);
  k_oproj <<<dim3(128, 16), 256, 0, stream>>>(aws, wo, bo, (float*)d_out);
}

// Round 4
// 362.164 us; speedup vs baseline: 1.8704x; 1.8704x over previous
//
#include <hip/hip_runtime.h>

typedef unsigned short u16;
typedef short  bfrag  __attribute__((ext_vector_type(8), may_alias)); // 8 bf16 (MFMA A/B)
typedef unsigned long long ull_a __attribute__((may_alias));
typedef int    int_a  __attribute__((may_alias));
typedef float  f4_a   __attribute__((ext_vector_type(4), may_alias));
typedef __attribute__((ext_vector_type(4)))  float facc4;   // 16x16 C/D
typedef __attribute__((ext_vector_type(16))) float facc16;  // 32x32 C/D

#define SEQ   2048
#define NHEAD 16
#define HD    64
#define DM    1024
#define BH    64        // B*NHEAD
#define NTOK  8192      // B*SEQ

__device__ __forceinline__ u16 f2bf(float f){
  union { float f; unsigned u; } x; x.f = f;
  unsigned r = x.u + 0x7FFFu + ((x.u >> 16) & 1u);
  return (u16)(r >> 16);
}
// load 8 consecutive f32 -> bf16 MFMA half-fragment
__device__ __forceinline__ bfrag ld8f(const float* p){
  f4_a a = *(const f4_a*)p;
  f4_a b = *(const f4_a*)(p + 4);
  bfrag r;
  r[0] = (short)f2bf(a[0]); r[1] = (short)f2bf(a[1]);
  r[2] = (short)f2bf(a[2]); r[3] = (short)f2bf(a[3]);
  r[4] = (short)f2bf(b[0]); r[5] = (short)f2bf(b[1]);
  r[6] = (short)f2bf(b[2]); r[7] = (short)f2bf(b[3]);
  return r;
}
__device__ __forceinline__ unsigned long long pack4(u16 a, u16 b, u16 c, u16 d){
  return (unsigned long long)a | ((unsigned long long)b << 16)
       | ((unsigned long long)c << 32) | ((unsigned long long)d << 48);
}
// async global->LDS, 16B per lane; LDS dest = wave-uniform base + lane*16
__device__ __forceinline__ void stage16(const u16* g, u16* l){
  __builtin_amdgcn_global_load_lds((const __attribute__((address_space(1))) void*)g,
                                   (__attribute__((address_space(3))) void*)l, 16, 0, 0);
}

// ---------------------------------------------------------------------------
// Kernel 1: per-head QKV projection (f32 in, bf16 out). One token per wave.
__global__ __launch_bounds__(256) void k_proj(
  const float* __restrict__ vin, const float* __restrict__ kin, const float* __restrict__ qin,
  const float* __restrict__ wq, const float* __restrict__ bq,
  const float* __restrict__ wk, const float* __restrict__ bk,
  const float* __restrict__ wv, const float* __restrict__ bv,
  u16* __restrict__ qo, u16* __restrict__ ko, u16* __restrict__ vo)
{
  int tid  = threadIdx.x;
  int wid  = tid >> 6, lane = tid & 63;
  int quad = lane >> 4, col = lane & 15;
  int token = blockIdx.x * 4 + wid;
  int b = token >> 11, s = token & 2047;
  long xbase = (long)token * DM;

  bfrag aq[2], ak[2], av[2];
  #pragma unroll
  for (int ks = 0; ks < 2; ks++){
    long off = xbase + (long)col * HD + ks*32 + quad*8;   // A[m=col(head)][e chunk]
    aq[ks] = ld8f(qin + off);
    ak[ks] = ld8f(kin + off);
    av[ks] = ld8f(vin + off);
  }
  #pragma unroll
  for (int ns = 0; ns < 4; ns++){
    facc4 accq = {0.f,0.f,0.f,0.f}, acck = {0.f,0.f,0.f,0.f}, accv = {0.f,0.f,0.f,0.f};
    #pragma unroll
    for (int ks = 0; ks < 2; ks++){
      long woff = (long)(ns*16 + col) * HD + ks*32 + quad*8;  // B[n=d][e chunk] = w[d][e]
      accq = __builtin_amdgcn_mfma_f32_16x16x32_bf16(aq[ks], ld8f(wq + woff), accq, 0,0,0);
      acck = __builtin_amdgcn_mfma_f32_16x16x32_bf16(ak[ks], ld8f(wk + woff), acck, 0,0,0);
      accv = __builtin_amdgcn_mfma_f32_16x16x32_bf16(av[ks], ld8f(wv + woff), accv, 0,0,0);
    }
    int d = ns*16 + col;
    float fbq = bq[d], fbk = bk[d], fbv = bv[d];
    #pragma unroll
    for (int r = 0; r < 4; r++){
      int h = quad*4 + r;                                   // C row = head
      long o = ((long)(b*NHEAD + h) * SEQ + s) * HD + d;    // [B,H,S,D]
      qo[o] = f2bf(accq[r] + fbq);
      ko[o] = f2bf(acck[r] + fbk);
      vo[o] = f2bf(accv[r] + fbv);
    }
  }
}

// ---------------------------------------------------------------------------
// Kernel 2: V transpose [BH][S][D] -> [BH][D][S] (bf16).
__global__ __launch_bounds__(256) void k_vtrans(
  const u16* __restrict__ vin, u16* __restrict__ vt)
{
  __shared__ __align__(16) u16 T[64*66];  // [s][d], stride 66
  int tid = threadIdx.x;
  int s0  = blockIdx.x * 64;
  int bh  = blockIdx.y;
  long ibase = ((long)bh * SEQ + s0) * HD;
  #pragma unroll
  for (int i = 0; i < 2; i++){
    int j = (tid + 256*i) * 8;
    int r = j >> 6, c = j & 63;
    bfrag v8 = *(const bfrag*)(vin + ibase + (long)r*HD + c);
    union { bfrag v; int w[4]; } u; u.v = v8;
    int_a* tp = (int_a*)&T[r*66 + c];      // 4B-aligned (c multiple of 8)
    tp[0] = u.w[0]; tp[1] = u.w[1]; tp[2] = u.w[2]; tp[3] = u.w[3];
  }
  __syncthreads();
  long obase = (long)bh * HD * SEQ + s0;
  #pragma unroll
  for (int it = 0; it < 16; it++){
    int d  = (it << 2) + (tid >> 6);
    int ss = tid & 63;
    vt[obase + (long)d * SEQ + ss] = T[ss*66 + d];   // coalesced store
  }
}

// ---------------------------------------------------------------------------
// Kernel 3: flash attention, transposed formulation with MFMA 32x32x16 (bf16 ws).
__global__ __launch_bounds__(256) void k_attn(
  const u16* __restrict__ qws, const u16* __restrict__ kws, const u16* __restrict__ vt,
  u16* __restrict__ aout)
{
  __shared__ __align__(16) u16 Kt[64*72];       // [key][e]
  __shared__ __align__(16) u16 Vt[64*72];       // [d][key]  (vt pre-transposed)
  __shared__ __align__(16) u16 Pt[4][32*72];    // per-wave [q][key]
  int tid = threadIdx.x;
  int wid = tid >> 6, lane = tid & 63;
  int ln = lane & 31, hh = lane >> 5;
  int bh = blockIdx.y;
  int q0 = blockIdx.x * 128 + wid * 32;
  long base = (long)bh * SEQ * HD;    // same element offset for qws/kws/vt

  bfrag qf[4];                        // B frag: Qᵀ[e][q], lane n=ln=q, k=e chunk
  #pragma unroll
  for (int ks = 0; ks < 4; ks++)
    qf[ks] = *(const bfrag*)(qws + base + (long)(q0 + ln)*HD + ks*16 + hh*8);

  facc16 OO0, OO1;
  #pragma unroll
  for (int r = 0; r < 16; r++){ OO0[r] = 0.f; OO1[r] = 0.f; }
  float m_ = -1e30f, l_ = 0.f;
  const float cs = 0.03125f * 1.4426950408889634f;  // (1/sqrt(1024)) * log2(e)

  for (int kt = 0; kt < 32; kt++){
    int k0 = kt * 64;
    __syncthreads();                      // prior tile's Vt reads done
    #pragma unroll
    for (int i = 0; i < 2; i++){
      int j = (tid + 256*i) * 8;
      int r = j >> 6, c = j & 63;
      *(bfrag*)&Kt[r*72 + c] = *(const bfrag*)(kws + base + (long)(k0 + r)*HD + c);
      *(bfrag*)&Vt[r*72 + c] = *(const bfrag*)(vt  + base + (long)r*SEQ + k0 + c);
    }
    __syncthreads();                      // staging visible

    // Eᵀ[key][q]: A = K[key][e] from LDS, B = Qᵀ from registers
    facc16 E0, E1;
    #pragma unroll
    for (int r = 0; r < 16; r++){ E0[r] = 0.f; E1[r] = 0.f; }
    #pragma unroll
    for (int ks = 0; ks < 4; ks++){
      bfrag kf0 = *(const bfrag*)&Kt[ ln      *72 + ks*16 + hh*8];
      bfrag kf1 = *(const bfrag*)&Kt[(32 + ln)*72 + ks*16 + hh*8];
      E0 = __builtin_amdgcn_mfma_f32_32x32x16_bf16(kf0, qf[ks], E0, 0,0,0);
      E1 = __builtin_amdgcn_mfma_f32_32x32x16_bf16(kf1, qf[ks], E1, 0,0,0);
    }

    // online softmax: lane owns q-row = ln; partner lane (^32) holds other 32 keys
    float tmax = E0[0];
    #pragma unroll
    for (int r = 1; r < 16; r++) tmax = fmaxf(tmax, E0[r]);
    #pragma unroll
    for (int r = 0; r < 16; r++) tmax = fmaxf(tmax, E1[r]);
    tmax = fmaxf(tmax, __shfl_xor(tmax, 32, 64));
    float Mn = fmaxf(m_, cs * tmax);
    float alpha = __builtin_amdgcn_exp2f(m_ - Mn);
    m_ = Mn;
    float rs = 0.f;
    #pragma unroll
    for (int r = 0; r < 16; r++){
      float p0 = __builtin_amdgcn_exp2f(cs*E0[r] - Mn);
      float p1 = __builtin_amdgcn_exp2f(cs*E1[r] - Mn);
      E0[r] = p0; E1[r] = p1; rs += p0 + p1;
    }
    rs += __shfl_xor(rs, 32, 64);
    l_ = l_ * alpha + rs;
    #pragma unroll
    for (int r = 0; r < 16; r++){ OO0[r] *= alpha; OO1[r] *= alpha; }

    // write Pᵀ C-layout -> Pt[q][key]
    u16* pw = &Pt[wid][ln*72];
    #pragma unroll
    for (int g = 0; g < 4; g++){
      *(ull_a*)(pw +      8*g + 4*hh) =
        pack4(f2bf(E0[4*g]), f2bf(E0[4*g+1]), f2bf(E0[4*g+2]), f2bf(E0[4*g+3]));
      *(ull_a*)(pw + 32 + 8*g + 4*hh) =
        pack4(f2bf(E1[4*g]), f2bf(E1[4*g+1]), f2bf(E1[4*g+2]), f2bf(E1[4*g+3]));
    }
    __syncthreads();   // P visible

    // Oᵀ[dv][q] += Vᵀ·Pᵀ
    bfrag pf[4];
    #pragma unroll
    for (int ks = 0; ks < 4; ks++)
      pf[ks] = *(const bfrag*)&Pt[wid][ln*72 + ks*16 + hh*8];
    #pragma unroll
    for (int ks = 0; ks < 4; ks++){
      bfrag vf0 = *(const bfrag*)&Vt[ ln      *72 + ks*16 + hh*8];
      bfrag vf1 = *(const bfrag*)&Vt[(32 + ln)*72 + ks*16 + hh*8];
      OO0 = __builtin_amdgcn_mfma_f32_32x32x16_bf16(vf0, pf[ks], OO0, 0,0,0);
      OO1 = __builtin_amdgcn_mfma_f32_32x32x16_bf16(vf1, pf[ks], OO1, 0,0,0);
    }
  }

  // epilogue: O[q][dv] = OOᵀ / l; store [B,S,H,D] bf16
  float inv = 1.0f / l_;
  int b_ = bh >> 4, h_ = bh & 15;
  long orow = ((long)(b_ * SEQ + q0 + ln) * NHEAD + h_) * HD;
  #pragma unroll
  for (int g = 0; g < 4; g++){
    *(ull_a*)(aout + orow +      8*g + 4*hh) =
      pack4(f2bf(OO0[4*g]*inv), f2bf(OO0[4*g+1]*inv), f2bf(OO0[4*g+2]*inv), f2bf(OO0[4*g+3]*inv));
    *(ull_a*)(aout + orow + 32 + 8*g + 4*hh) =
      pack4(f2bf(OO1[4*g]*inv), f2bf(OO1[4*g+1]*inv), f2bf(OO1[4*g+2]*inv), f2bf(OO1[4*g+3]*inv));
  }
}

// ---------------------------------------------------------------------------
// Kernel 4a: convert wo f32 [1024][1024] -> bf16 (same layout), once.
__global__ __launch_bounds__(256) void k_wconv(
  const float* __restrict__ wo, u16* __restrict__ wob)
{
  long i = ((long)blockIdx.x * 256 + threadIdx.x) * 8;
  f4_a a = *(const f4_a*)(wo + i);
  f4_a b = *(const f4_a*)(wo + i + 4);
  ull_a* p = (ull_a*)(wob + i);
  p[0] = pack4(f2bf(a[0]), f2bf(a[1]), f2bf(a[2]), f2bf(a[3]));
  p[1] = pack4(f2bf(b[0]), f2bf(b[1]), f2bf(b[2]), f2bf(b[3]));
}

// ---------------------------------------------------------------------------
// Kernel 4b: output projection out = A @ wo.T + bo, m97-style.
// A [8192][1024] bf16 (ws), Bw = wo_bf16 [1024][1024] (row n = wo row n),
// out f32. 128x128 tile, BK=64, global_load_lds staging, 4 waves x 4x4 acc.
__global__ __launch_bounds__(256) void k_oproj(
  const u16* __restrict__ A, const u16* __restrict__ Bw,
  const float* __restrict__ bo, float* __restrict__ out)
{
  __shared__ __align__(16) u16 As[128*64];   // [m][k] 16 KB
  __shared__ __align__(16) u16 Bs[128*64];   // [n][k] 16 KB
  int tid  = threadIdx.x;
  int wid  = tid >> 6, lane = tid & 63;
  int quad = lane >> 4, col = lane & 15;
  int m0 = blockIdx.x * 128;
  int n0 = blockIdx.y * 128;
  int wm = (wid & 1) * 64, wn = (wid >> 1) * 64;

  facc4 acc[4][4];
  #pragma unroll
  for (int i = 0; i < 4; i++)
    #pragma unroll
    for (int j = 0; j < 4; j++) acc[i][j] = {0.f,0.f,0.f,0.f};

  // staging map: instruction j stages rows [j*32+wid*8, +8), lane l -> row +l/8,
  // 16B chunk (l%8) within the 64-elem k-slice. LDS dest contiguous in lane order.
  int srow = wid*8 + (lane >> 3);
  int scol = (lane & 7) * 8;
  const u16* Ag = A  + (long)(m0 + srow) * DM + scol;
  const u16* Bg = Bw + (long)(n0 + srow) * DM + scol;

  for (int k0 = 0; k0 < DM; k0 += 64){
    __syncthreads();                       // prior tile's ds_reads done
    #pragma unroll
    for (int j = 0; j < 4; j++){
      stage16(Ag + (long)j*32*DM + k0, &As[(j*32 + wid*8)*64]);
      stage16(Bg + (long)j*32*DM + k0, &Bs[(j*32 + wid*8)*64]);
    }
    __syncthreads();                       // staging visible (vmcnt drained)

    #pragma unroll
    for (int ks = 0; ks < 2; ks++){
      bfrag af[4], bf[4];
      #pragma unroll
      for (int i = 0; i < 4; i++)
        af[i] = *(const bfrag*)&As[(wm + i*16 + col)*64 + ks*32 + quad*8];
      #pragma unroll
      for (int i = 0; i < 4; i++)
        bf[i] = *(const bfrag*)&Bs[(wn + i*16 + col)*64 + ks*32 + quad*8];
      #pragma unroll
      for (int i = 0; i < 4; i++)
        #pragma unroll
        for (int j = 0; j < 4; j++)
          acc[i][j] = __builtin_amdgcn_mfma_f32_16x16x32_bf16(af[i], bf[j], acc[i][j], 0,0,0);
    }
  }

  // epilogue: C row = m (quad*4+r), col = n (col)
  #pragma unroll
  for (int j = 0; j < 4; j++){
    int n = n0 + wn + j*16 + col;
    float bias = bo[n];
    #pragma unroll
    for (int i = 0; i < 4; i++){
      long mrow = m0 + wm + i*16 + quad*4;
      #pragma unroll
      for (int r = 0; r < 4; r++)
        out[(mrow + r) * DM + n] = acc[i][j][r] + bias;
    }
  }
}

// ---------------------------------------------------------------------------
extern "C" void kernel_launch(void* const* d_in, const int* in_sizes, int n_in,
                              void* d_out, int out_size, void* d_ws, size_t ws_size,
                              hipStream_t stream)
{
  const float* values = (const float*)d_in[0];
  const float* keys   = (const float*)d_in[1];
  const float* query  = (const float*)d_in[2];
  const float* wq = (const float*)d_in[3];
  const float* bq = (const float*)d_in[4];
  const float* wk = (const float*)d_in[5];
  const float* bk = (const float*)d_in[6];
  const float* wv = (const float*)d_in[7];
  const float* bv = (const float*)d_in[8];
  const float* wo = (const float*)d_in[9];
  const float* bo = (const float*)d_in[10];

  const long N = 8388608;             // B*H*S*D elements
  u16* qws  = (u16*)d_ws;             // bf16 intermediates
  u16* kws  = qws  + N;
  u16* vws  = kws  + N;
  u16* vtws = vws  + N;
  u16* aws  = vws;                    // reuse vws (dead after k_vtrans)
  u16* wob  = qws;                    // reuse qws (dead after k_attn): 64 MB total

  k_proj  <<<2048,          256, 0, stream>>>(values, keys, query, wq,bq, wk,bk, wv,bv,
                                              qws, kws, vws);
  k_vtrans<<<dim3(32, 64),  256, 0, stream>>>(vws, vtws);
  k_attn  <<<dim3(16, 64),  256, 0, stream>>>(qws, kws, vtws, aws);
  k_wconv <<<512,           256, 0, stream>>>(wo, wob);
  k_oproj <<<dim3(64, 8),   256, 0, stream>>>(aws, wob, bo, (float*)d_out);
}